// Round 3
// baseline (575.391 us; speedup 1.0000x reference)
//
#include <hip/hip_runtime.h>
#include <hip/hip_bf16.h>
#include <stdint.h>

// Problem dims (fixed by setup_inputs)
#define T_DIM 2048
#define I_DIM 4096
#define O_DIM 4096
#define R_DIM 16
#define QBLK  32

typedef __bf16 bf16x8 __attribute__((ext_vector_type(8)));
typedef float  floatx4 __attribute__((ext_vector_type(4)));
typedef unsigned short ushort_t;

#define AS1 __attribute__((address_space(1)))
#define AS3 __attribute__((address_space(3)))

__device__ __forceinline__ ushort_t f2bf(float f) {
  unsigned u = __float_as_uint(f);
  u += 0x7FFFu + ((u >> 16) & 1u);   // round-to-nearest-even
  return (ushort_t)(u >> 16);
}

__device__ __forceinline__ float dot4(float4 a, float4 b) {
  return a.x * b.x + a.y * b.y + a.z * b.z + a.w * b.w;
}

// ------------- merged prep: xd | xb=bf16(x) | wb=dequant(q)
// R8: ZERO shared memory anywhere in this kernel. R5-R7 allocated 32KB
// __shared__ in ALL 12544 blocks (5 blocks/CU occupancy cap on a pure
// streaming kernel, suspect for prep's ~150us vs ~23us roofline). The xd
// branch now reads `down` (256KB, L2-resident) directly from global
// instead of LDS-staging it. Block ranges: [0,256) xd, [256,4352) prep_x,
// [4352,12544) prep_w.
__global__ __launch_bounds__(256) void k_prep(const float* __restrict__ x,
                                              const int* __restrict__ q,
                                              const float* __restrict__ scales,
                                              const float* __restrict__ down,
                                              const float* __restrict__ alphap,
                                              ushort_t* __restrict__ xb,
                                              ushort_t* __restrict__ wb,
                                              float* __restrict__ xd) {
  const int b = blockIdx.x, tid = threadIdx.x;

  if (b >= 256 && b < 4352) {                 // ---- prep_x
    int idx = (b - 256) * 256 + tid;          // 8-element chunk id
    const float4* xp = (const float4*)x;
    float4 a = xp[idx * 2], c = xp[idx * 2 + 1];
    union { ushort_t u[8]; uint4 v; } r;
    r.u[0] = f2bf(a.x); r.u[1] = f2bf(a.y); r.u[2] = f2bf(a.z); r.u[3] = f2bf(a.w);
    r.u[4] = f2bf(c.x); r.u[5] = f2bf(c.y); r.u[6] = f2bf(c.z); r.u[7] = f2bf(c.w);
    ((uint4*)xb)[idx] = r.v;
    return;
  }
  if (b >= 4352) {                            // ---- prep_w
    int idx = (b - 4352) * 256 + tid;
    int o  = idx >> 9;
    int i0 = (idx & 511) * 8;
    float s = scales[o * (I_DIM / QBLK) + (i0 >> 5)];
    const int4* qp = (const int4*)(q + (size_t)o * I_DIM + i0);
    int4 q0 = qp[0], q1 = qp[1];
    union { ushort_t u[8]; uint4 v; } r;
    r.u[0] = f2bf((float)(q0.x - 8) * s); r.u[1] = f2bf((float)(q0.y - 8) * s);
    r.u[2] = f2bf((float)(q0.z - 8) * s); r.u[3] = f2bf((float)(q0.w - 8) * s);
    r.u[4] = f2bf((float)(q1.x - 8) * s); r.u[5] = f2bf((float)(q1.y - 8) * s);
    r.u[6] = f2bf((float)(q1.z - 8) * s); r.u[7] = f2bf((float)(q1.w - 8) * s);
    ((uint4*)wb)[idx] = r.v;
    return;
  }
  // ---- xd = alpha * (x @ down^T), 8 tokens per block, b in [0,256)
  // No LDS: down rows read directly (L2-resident after first touches).
  {
    const int blk = b;
    const int tl = tid >> 5, s = tid & 31;
    const int t = blk * 8 + tl;
    float acc[16];
#pragma unroll
    for (int r = 0; r < 16; ++r) acc[r] = 0.f;
    for (int c = 0; c < 8; ++c) {
      const int ib = c * 512;
#pragma unroll
      for (int j = 0; j < 4; ++j) {
        float4 xv = ((const float4*)(x + (size_t)t * I_DIM + ib))[s + 32 * j];
#pragma unroll
        for (int r = 0; r < 16; ++r) {
          float4 dv = ((const float4*)(down + (size_t)r * I_DIM + ib))[s + 32 * j];
          acc[r] += dot4(xv, dv);
        }
      }
    }
    const float al = alphap[0];
#pragma unroll
    for (int r = 0; r < 16; ++r) {
      float v = acc[r];
      v += __shfl_down(v, 16, 32);
      v += __shfl_down(v, 8, 32);
      v += __shfl_down(v, 4, 32);
      v += __shfl_down(v, 2, 32);
      v += __shfl_down(v, 1, 32);
      if (s == 0) xd[t * 16 + r] = v * al;
    }
  }
}

// ======================= R8 main GEMM ==================================
// R5/R6/R7 all landed at exactly ~297us (232 TF) with MfmaUtil 9.5%
// across three different schedules -> the schedule was never the limiter.
// R8 is a faithful replica of the PROVEN m97 structure (learn_hip m102:
// 833 TF at N=4096 at this block density):
//  - 128x128 tile, BK=64, 4 waves 2x2, per-wave 64x64 (acc 4x4).
//  - Single-buffered LDS: As/Bs 16KB each = 32KB -> with ~128 VGPR this
//    gives 4 blocks/CU (double R5-R7's residency; m102 shape curve says
//    residency dominates this latency-bound structure).
//  - Plain __syncthreads() (compiler emits the vmcnt(0) drain; the known
//    ~20% tax of this structure), C++ fragment reads, compiler waitcnt.
//  - Both-sides XOR granule swizzle (store col-granule g^(r&7), read
//    c^(m&7)) -> 2-way LDS read aliasing = free (m136).
//  - Plain 2D grid (32,16); no XCD swizzle (L3-fit working set, m160).

__global__ __launch_bounds__(256) void k_gemm(const ushort_t* __restrict__ xb,
                                              const ushort_t* __restrict__ wb,
                                              const float* __restrict__ bias,
                                              const float* __restrict__ xd,
                                              const float* __restrict__ up,
                                              float* __restrict__ y) {
  __shared__ __align__(16) ushort_t As[128 * 64];   // 16 KB
  __shared__ __align__(16) ushort_t Bs[128 * 64];   // 16 KB

  const int tid = threadIdx.x;
  const int wv = tid >> 6, lane = tid & 63;
  const int quad = lane >> 4, m16 = lane & 15;
  const int wm = wv >> 1, wn = wv & 1;

  const int oT = blockIdx.x * 128, tT = blockIdx.y * 128;
  const ushort_t* ap = xb + (size_t)tT * I_DIM;
  const ushort_t* bp = wb + (size_t)oT * I_DIM;

  floatx4 acc[4][4] = {};

  for (int kt = 0; kt < I_DIM / 64; ++kt) {
    const int k0 = kt * 64;
    // Stage A: 128 rows x 64 cols bf16 = 1024 granules; 4 instr/thread.
    // LDS dest linear (wave-uniform base + lane*16); global src granule
    // pre-swizzled with involution g -> g ^ (r&7).
#pragma unroll
    for (int it = 0; it < 4; ++it) {
      const int seg_base = it * 256 + wv * 64;       // wave-uniform
      const int seg = seg_base + lane;
      const int r  = seg >> 3;
      const int cg = (seg & 7) ^ (r & 7);
      __builtin_amdgcn_global_load_lds(
          (const AS1 char*)(ap + (size_t)r * I_DIM + k0 + cg * 8),
          (AS3 char*)(As + seg_base * 8), 16, 0, 0);
    }
#pragma unroll
    for (int it = 0; it < 4; ++it) {
      const int seg_base = it * 256 + wv * 64;
      const int seg = seg_base + lane;
      const int r  = seg >> 3;
      const int cg = (seg & 7) ^ (r & 7);
      __builtin_amdgcn_global_load_lds(
          (const AS1 char*)(bp + (size_t)r * I_DIM + k0 + cg * 8),
          (AS3 char*)(Bs + seg_base * 8), 16, 0, 0);
    }
    __syncthreads();   // drains vmcnt(0): the m97 structural tax

#pragma unroll
    for (int ks2 = 0; ks2 < 2; ++ks2) {              // two K=32 halves
      const int c = ks2 * 4 + quad;
      bf16x8 af[4], bfr[4];
#pragma unroll
      for (int im = 0; im < 4; ++im) {
        const int m = wm * 64 + im * 16 + m16;
        af[im] = *(const bf16x8*)(As + (m * 8 + (c ^ (m & 7))) * 8);
      }
#pragma unroll
      for (int in_ = 0; in_ < 4; ++in_) {
        const int n = wn * 64 + in_ * 16 + m16;
        bfr[in_] = *(const bf16x8*)(Bs + (n * 8 + (c ^ (n & 7))) * 8);
      }
#pragma unroll
      for (int im = 0; im < 4; ++im)
#pragma unroll
        for (int in_ = 0; in_ < 4; ++in_)
          acc[im][in_] = __builtin_amdgcn_mfma_f32_16x16x32_bf16(
              af[im], bfr[in_], acc[im][in_], 0, 0, 0);
    }
    __syncthreads();
  }

  // Epilogue: y[t][o] = acc + dot16(xd[t], up[o]) + bias[o]
  // C/D layout: row = quad*4+reg, col = lane&15 (m89-verified).
#pragma unroll
  for (int im = 0; im < 4; ++im) {
#pragma unroll
    for (int reg = 0; reg < 4; ++reg) {
      const int t = tT + wm * 64 + im * 16 + quad * 4 + reg;
      const float4* xr = (const float4*)(xd + t * 16);
      float4 x0 = xr[0], x1 = xr[1], x2 = xr[2], x3 = xr[3];
#pragma unroll
      for (int in_ = 0; in_ < 4; ++in_) {
        const int o = oT + wn * 64 + in_ * 16 + m16;
        const float4* ur = (const float4*)(up + (size_t)o * R_DIM);
        float lv = dot4(x0, ur[0]) + dot4(x1, ur[1]) +
                   dot4(x2, ur[2]) + dot4(x3, ur[3]);
        y[(size_t)t * O_DIM + o] = acc[im][in_][reg] + lv + bias[o];
      }
    }
  }
}

extern "C" void kernel_launch(void* const* d_in, const int* in_sizes, int n_in,
                              void* d_out, int out_size, void* d_ws, size_t ws_size,
                              hipStream_t stream) {
  const float* x      = (const float*)d_in[0];
  const int*   q      = (const int*)d_in[1];
  const float* scales = (const float*)d_in[2];
  const float* up     = (const float*)d_in[3];
  const float* down   = (const float*)d_in[4];
  const float* alpha  = (const float*)d_in[5];
  const float* bias   = (const float*)d_in[6];
  float* y = (float*)d_out;

  // ws layout: xb bf16 [T,I] (16 MB) | wb bf16 [O,I] (32 MB) | xd f32 [T,16]
  ushort_t* xb = (ushort_t*)d_ws;
  ushort_t* wb = (ushort_t*)((char*)d_ws + (size_t)T_DIM * I_DIM * 2);
  float*    xd = (float*)((char*)d_ws + (size_t)T_DIM * I_DIM * 2 + (size_t)O_DIM * I_DIM * 2);

  hipLaunchKernelGGL(k_prep, dim3(256 + 4096 + 8192), dim3(256), 0, stream,
                     x, q, scales, down, alpha, xb, wb, xd);
  hipLaunchKernelGGL(k_gemm, dim3(O_DIM / 128, T_DIM / 128), dim3(256), 0, stream,
                     xb, wb, bias, xd, up, y);
}

// Round 4
// 435.347 us; speedup vs baseline: 1.3217x; 1.3217x over previous
//
#include <hip/hip_runtime.h>
#include <hip/hip_bf16.h>
#include <stdint.h>

// Problem dims (fixed by setup_inputs)
#define T_DIM 2048
#define I_DIM 4096
#define O_DIM 4096
#define R_DIM 16
#define QBLK  32

typedef __bf16 bf16x8 __attribute__((ext_vector_type(8)));
typedef float  floatx4 __attribute__((ext_vector_type(4)));
typedef unsigned short ushort_t;

#define AS1 __attribute__((address_space(1)))
#define AS3 __attribute__((address_space(3)))

__device__ __forceinline__ ushort_t f2bf(float f) {
  unsigned u = __float_as_uint(f);
  u += 0x7FFFu + ((u >> 16) & 1u);   // round-to-nearest-even
  return (ushort_t)(u >> 16);
}

__device__ __forceinline__ float dot4(float4 a, float4 b) {
  return a.x * b.x + a.y * b.y + a.z * b.z + a.w * b.w;
}

// ---------------- k_stream: xb=bf16(x) | wb=dequant(q). ZERO LDS. ------
// Split from k_xd so the 12288 streaming blocks carry no LDS allocation
// and so rocprof reports prep phases separately.
__global__ __launch_bounds__(256) void k_stream(const float* __restrict__ x,
                                                const int* __restrict__ q,
                                                const float* __restrict__ scales,
                                                ushort_t* __restrict__ xb,
                                                ushort_t* __restrict__ wb) {
  const int b = blockIdx.x, tid = threadIdx.x;
  if (b < 4096) {                             // ---- prep_x
    int idx = b * 256 + tid;                  // 8-element chunk id
    const float4* xp = (const float4*)x;
    float4 a = xp[idx * 2], c = xp[idx * 2 + 1];
    union { ushort_t u[8]; uint4 v; } r;
    r.u[0] = f2bf(a.x); r.u[1] = f2bf(a.y); r.u[2] = f2bf(a.z); r.u[3] = f2bf(a.w);
    r.u[4] = f2bf(c.x); r.u[5] = f2bf(c.y); r.u[6] = f2bf(c.z); r.u[7] = f2bf(c.w);
    ((uint4*)xb)[idx] = r.v;
    return;
  }
  {                                           // ---- prep_w
    int idx = (b - 4096) * 256 + tid;
    int o  = idx >> 9;
    int i0 = (idx & 511) * 8;
    float s = scales[o * (I_DIM / QBLK) + (i0 >> 5)];
    const int4* qp = (const int4*)(q + (size_t)o * I_DIM + i0);
    int4 q0 = qp[0], q1 = qp[1];
    union { ushort_t u[8]; uint4 v; } r;
    r.u[0] = f2bf((float)(q0.x - 8) * s); r.u[1] = f2bf((float)(q0.y - 8) * s);
    r.u[2] = f2bf((float)(q0.z - 8) * s); r.u[3] = f2bf((float)(q0.w - 8) * s);
    r.u[4] = f2bf((float)(q1.x - 8) * s); r.u[5] = f2bf((float)(q1.y - 8) * s);
    r.u[6] = f2bf((float)(q1.z - 8) * s); r.u[7] = f2bf((float)(q1.w - 8) * s);
    ((uint4*)wb)[idx] = r.v;
  }
}

// ---------------- k_xd: xd = alpha * (x @ down^T) ----------------------
// R2's proven LDS-staged version, now its own kernel (256 blocks only).
__global__ __launch_bounds__(256) void k_xd(const float* __restrict__ x,
                                            const float* __restrict__ down,
                                            const float* __restrict__ alphap,
                                            float* __restrict__ xd) {
  __shared__ float ds[16 * 512];              // 32 KB
  const int b = blockIdx.x, tid = threadIdx.x;
  const int tl = tid >> 5, s = tid & 31;
  const int t = b * 8 + tl;
  float acc[16];
#pragma unroll
  for (int r = 0; r < 16; ++r) acc[r] = 0.f;
  for (int c = 0; c < 8; ++c) {
    const int ib = c * 512;
    __syncthreads();
#pragma unroll
    for (int j = 0; j < 8; ++j) {
      int e = j * 256 + tid;
      int r = e >> 7, col = e & 127;
      ((float4*)ds)[e] = ((const float4*)(down + (size_t)r * I_DIM + ib))[col];
    }
    __syncthreads();
#pragma unroll
    for (int j = 0; j < 4; ++j) {
      float4 xv = ((const float4*)(x + (size_t)t * I_DIM + ib))[s + 32 * j];
#pragma unroll
      for (int r = 0; r < 16; ++r) {
        float4 dv = ((const float4*)ds)[r * 128 + s + 32 * j];
        acc[r] += dot4(xv, dv);
      }
    }
  }
  const float al = alphap[0];
#pragma unroll
  for (int r = 0; r < 16; ++r) {
    float v = acc[r];
    v += __shfl_down(v, 16, 32);
    v += __shfl_down(v, 8, 32);
    v += __shfl_down(v, 4, 32);
    v += __shfl_down(v, 2, 32);
    v += __shfl_down(v, 1, 32);
    if (s == 0) xd[t * 16 + r] = v * al;
  }
}

// ======================= R9 main GEMM ==================================
// R5-R8 all ~230 TF with 4-wave blocks (2 waves/SIMD barrier convoys).
// m201's template proves 1 block/CU is FINE when the block is BIG:
// 512 threads / 8 waves + counted-vmcnt depth. R9 ports that:
//  - BM=128(T) x BN=256(O), BK=64, grid (16,16)=256 blocks = 1/CU.
//  - 8 waves 2(M)x4(N); per-wave 64x64, acc[4][4] (verified math reused).
//  - Ring-3 LDS: 3 x (16KB A + 32KB B) = 144KB static (<=160KB HW;
//    m201 precedent 128KB). Stage tile kt+2 while computing kt.
//  - ONE barrier per K-tile; vmcnt(6) never-drain (T4); lgkmcnt(8)
//    mid-tile so half1 ds_reads hide under half0's 16 MFMAs ->
//    32 MFMA per barrier crossing.
//  - 8-slot XOR granule swizzle (R8-verified: 0 bank conflicts).
//  - Inline-asm ds_read_b128 + rule-18 lgkm/sched_barrier fences;
//    setprio(1) around MFMA bursts (T5).

#define BK 64
#define NT (I_DIM / BK)        // 64 K-tiles
#define ASZ (128 * BK)         // A tile elems (16KB)
#define BSZ (256 * BK)         // B tile elems (32KB)

__device__ __forceinline__ bf16x8 lds_read16(unsigned addr) {
  bf16x8 d;
  asm volatile("ds_read_b128 %0, %1" : "=v"(d) : "v"(addr));
  return d;
}

__device__ __forceinline__ void stage6(const ushort_t* __restrict__ ga,
                                       const ushort_t* __restrict__ gb,
                                       ushort_t* Ast, ushort_t* Bst, int tid) {
  // A: 128x64 bf16 = 1024 granules -> 2/thread; B: 256x64 = 2048 -> 4/thread.
  // LDS dest linear (uniform base + lane*16); global granule pre-swizzled
  // with involution g -> g ^ (r&7).
#pragma unroll
  for (int it = 0; it < 2; ++it) {
    const int seg = it * 512 + tid;
    const int r = seg >> 3, cg = (seg & 7) ^ (r & 7);
    __builtin_amdgcn_global_load_lds(
        (const AS1 char*)(ga + (size_t)r * I_DIM + cg * 8),
        (AS3 char*)(Ast + (size_t)seg * 8), 16, 0, 0);
  }
#pragma unroll
  for (int it = 0; it < 4; ++it) {
    const int seg = it * 512 + tid;
    const int r = seg >> 3, cg = (seg & 7) ^ (r & 7);
    __builtin_amdgcn_global_load_lds(
        (const AS1 char*)(gb + (size_t)r * I_DIM + cg * 8),
        (AS3 char*)(Bst + (size_t)seg * 8), 16, 0, 0);
  }
}

// One K-tile. VM: vmcnt at tile end (6 steady / 0 / -1 none). STG: stage kt+2.
template<int VM, bool STG>
__device__ __forceinline__ void ktile(unsigned aB, unsigned bB,
                                      ushort_t* Ast, ushort_t* Bst,
                                      const ushort_t* ga, const ushort_t* gb,
                                      floatx4 (&acc)[4][4], int tid) {
  const int lane = tid & 63, wv = tid >> 6;
  const int quad = lane >> 4, m16 = lane & 15;
  const int wm = wv >> 2, wn = wv & 3;

  if constexpr (STG) stage6(ga, gb, Ast, Bst, tid);

  bf16x8 a0[4], b0[4], a1[4], b1[4];
#pragma unroll
  for (int i = 0; i < 4; ++i) {
    const int m = wm * 64 + i * 16 + m16;
    a0[i] = lds_read16(aB + (unsigned)((m * 8 + (quad ^ (m & 7))) * 16));
  }
#pragma unroll
  for (int i = 0; i < 4; ++i) {
    const int n = wn * 64 + i * 16 + m16;
    b0[i] = lds_read16(bB + (unsigned)((n * 8 + (quad ^ (n & 7))) * 16));
  }
#pragma unroll
  for (int i = 0; i < 4; ++i) {
    const int m = wm * 64 + i * 16 + m16;
    a1[i] = lds_read16(aB + (unsigned)((m * 8 + ((4 + quad) ^ (m & 7))) * 16));
  }
#pragma unroll
  for (int i = 0; i < 4; ++i) {
    const int n = wn * 64 + i * 16 + m16;
    b1[i] = lds_read16(bB + (unsigned)((n * 8 + ((4 + quad) ^ (n & 7))) * 16));
  }
  // half0 frags (first 8 ds_reads, in-order retire) ready:
  asm volatile("s_waitcnt lgkmcnt(8)" ::: "memory");
  __builtin_amdgcn_sched_barrier(0);
  __builtin_amdgcn_s_setprio(1);
#pragma unroll
  for (int i = 0; i < 4; ++i)
#pragma unroll
    for (int j = 0; j < 4; ++j)
      acc[i][j] = __builtin_amdgcn_mfma_f32_16x16x32_bf16(a0[i], b0[j], acc[i][j], 0, 0, 0);
  __builtin_amdgcn_s_setprio(0);
  asm volatile("s_waitcnt lgkmcnt(0)" ::: "memory");
  __builtin_amdgcn_sched_barrier(0);
  __builtin_amdgcn_s_setprio(1);
#pragma unroll
  for (int i = 0; i < 4; ++i)
#pragma unroll
    for (int j = 0; j < 4; ++j)
      acc[i][j] = __builtin_amdgcn_mfma_f32_16x16x32_bf16(a1[i], b1[j], acc[i][j], 0, 0, 0);
  __builtin_amdgcn_s_setprio(0);
  if constexpr (VM == 6)      asm volatile("s_waitcnt vmcnt(6)" ::: "memory");
  else if constexpr (VM == 0) asm volatile("s_waitcnt vmcnt(0)" ::: "memory");
  if constexpr (VM >= 0) __builtin_amdgcn_sched_barrier(0);
  __builtin_amdgcn_s_barrier();
}

__global__ __launch_bounds__(512, 2) void k_gemm(const ushort_t* __restrict__ xb,
                                                 const ushort_t* __restrict__ wb,
                                                 const float* __restrict__ bias,
                                                 const float* __restrict__ xd,
                                                 const float* __restrict__ up,
                                                 float* __restrict__ y) {
  __shared__ __align__(16) ushort_t As[3][ASZ];   // 48 KB
  __shared__ __align__(16) ushort_t Bs[3][BSZ];   // 96 KB

  const int tid = threadIdx.x;
  const int oT = blockIdx.x * 256, tT = blockIdx.y * 128;
  const ushort_t* ap = xb + (size_t)tT * I_DIM;
  const ushort_t* bp = wb + (size_t)oT * I_DIM;

  const unsigned aL = (unsigned)(uintptr_t)(AS3 ushort_t*)&As[0][0];
  const unsigned bL = (unsigned)(uintptr_t)(AS3 ushort_t*)&Bs[0][0];
  const unsigned aS0 = aL, aS1 = aL + ASZ * 2, aS2 = aL + ASZ * 4;
  const unsigned bS0 = bL, bS1 = bL + BSZ * 2, bS2 = bL + BSZ * 4;

  floatx4 acc[4][4] = {};

  // Prologue: stage tiles 0,1 (12 loads/thread); wait tile 0 (vmcnt 6).
  stage6(ap, bp, As[0], Bs[0], tid);
  stage6(ap + BK, bp + BK, As[1], Bs[1], tid);
  asm volatile("s_waitcnt vmcnt(6)" ::: "memory");
  __builtin_amdgcn_sched_barrier(0);
  __builtin_amdgcn_s_barrier();

  // Main loop: kt = 0..59 in triples (slots kt%3); stage kt+2.
  int kc = 2 * BK;
  for (int g = 0; g < 20; ++g) {
    ktile<6, true>(aS0, bS0, As[2], Bs[2], ap + kc, bp + kc, acc, tid); kc += BK;
    ktile<6, true>(aS1, bS1, As[0], Bs[0], ap + kc, bp + kc, acc, tid); kc += BK;
    ktile<6, true>(aS2, bS2, As[1], Bs[1], ap + kc, bp + kc, acc, tid); kc += BK;
  }
  // kt=60 (slot0, stage t62->slot2), kt=61 (slot1, stage t63->slot0)
  ktile<6, true>(aS0, bS0, As[2], Bs[2], ap + kc, bp + kc, acc, tid); kc += BK;
  ktile<6, true>(aS1, bS1, As[0], Bs[0], ap + kc, bp + kc, acc, tid);
  // kt=62 (slot2, drain t63), kt=63 (slot0)
  ktile<0, false>(aS2, bS2, nullptr, nullptr, nullptr, nullptr, acc, tid);
  ktile<-1, false>(aS0, bS0, nullptr, nullptr, nullptr, nullptr, acc, tid);

  // Epilogue: y[t][o] = acc + dot16(xd[t], up[o]) + bias[o]
  // C/D layout: row = quad*4+reg, col = lane&15 (m89-verified).
  const int lane = tid & 63, wv = tid >> 6;
  const int quad = lane >> 4, m16 = lane & 15;
  const int wm = wv >> 2, wn = wv & 3;
#pragma unroll
  for (int im = 0; im < 4; ++im) {
#pragma unroll
    for (int reg = 0; reg < 4; ++reg) {
      const int t = tT + wm * 64 + im * 16 + quad * 4 + reg;
      const float4* xr = (const float4*)(xd + t * 16);
      float4 x0 = xr[0], x1 = xr[1], x2 = xr[2], x3 = xr[3];
#pragma unroll
      for (int in_ = 0; in_ < 4; ++in_) {
        const int o = oT + wn * 64 + in_ * 16 + m16;
        const float4* ur = (const float4*)(up + (size_t)o * R_DIM);
        float lv = dot4(x0, ur[0]) + dot4(x1, ur[1]) +
                   dot4(x2, ur[2]) + dot4(x3, ur[3]);
        y[(size_t)t * O_DIM + o] = acc[im][in_][reg] + lv + bias[o];
      }
    }
  }
}

extern "C" void kernel_launch(void* const* d_in, const int* in_sizes, int n_in,
                              void* d_out, int out_size, void* d_ws, size_t ws_size,
                              hipStream_t stream) {
  const float* x      = (const float*)d_in[0];
  const int*   q      = (const int*)d_in[1];
  const float* scales = (const float*)d_in[2];
  const float* up     = (const float*)d_in[3];
  const float* down   = (const float*)d_in[4];
  const float* alpha  = (const float*)d_in[5];
  const float* bias   = (const float*)d_in[6];
  float* y = (float*)d_out;

  // ws layout: xb bf16 [T,I] (16 MB) | wb bf16 [O,I] (32 MB) | xd f32 [T,16]
  ushort_t* xb = (ushort_t*)d_ws;
  ushort_t* wb = (ushort_t*)((char*)d_ws + (size_t)T_DIM * I_DIM * 2);
  float*    xd = (float*)((char*)d_ws + (size_t)T_DIM * I_DIM * 2 + (size_t)O_DIM * I_DIM * 2);

  hipLaunchKernelGGL(k_stream, dim3(4096 + 8192), dim3(256), 0, stream,
                     x, q, scales, xb, wb);
  hipLaunchKernelGGL(k_xd, dim3(256), dim3(256), 0, stream, x, down, alpha, xd);
  hipLaunchKernelGGL(k_gemm, dim3(O_DIM / 256, T_DIM / 128), dim3(512), 0, stream,
                     xb, wb, bias, xd, up, y);
}